// Round 8
// baseline (666.453 us; speedup 1.0000x reference)
//
#include <hip/hip_runtime.h>
#include <hip/hip_bf16.h>

#define CIN   64
#define COUT  64
#define TT    512
#define FF    161
#define KTOT  576          // 9 * 64
#define TFSTR (TT*FF)      // 82432
#define FP_   168          // padded f dim of X2: fp = f+1, zeros at fp=0 and fp>=162

#define W2_BYTES  ((size_t)FF*COUT*KTOT*2)           // 11,870,208
#define X2_BYTES  ((size_t)8*TT*FP_*64*2)            // 88,080,384
#define TMP_BYTES ((size_t)8*FF*TT*COUT*2)           // 84,410,368
#define PW_BLOCKS 5796                               // 161*9216/256 u16x4 quads

typedef __bf16 bf16x8 __attribute__((ext_vector_type(8)));
typedef float  f32x4  __attribute__((ext_vector_type(4)));
typedef unsigned short u16x8 __attribute__((ext_vector_type(8)));
typedef unsigned short u16x4 __attribute__((ext_vector_type(4)));
typedef unsigned int   u32x2 __attribute__((ext_vector_type(2)));
typedef float f4u __attribute__((ext_vector_type(4), aligned(4)));

__device__ __forceinline__ unsigned short f2bf(float v) {
    union { float f; unsigned int u; } c; c.f = v;
    unsigned int u = c.u + 0x7FFFu + ((c.u >> 16) & 1u);   // RNE
    return (unsigned short)(u >> 16);
}
__device__ __forceinline__ float bf2f(unsigned short h) {
    union { unsigned int u; float f; } c; c.u = (unsigned)h << 16;
    return c.f;
}

// ---- fused prep: blocks [0, PW_BLOCKS) repack weights; rest transpose x ----
__global__ __launch_bounds__(256) void prep_fused(
    const float* __restrict__ ksrc, unsigned short* __restrict__ w2,
    const float* __restrict__ x, unsigned short* __restrict__ x2)
{
    __shared__ unsigned short Xs[64][172];      // 22,016 B
    int bx = blockIdx.x;
    int tid = threadIdx.x;

    if (bx < PW_BLOCKS) {                       // W2[f][o][k], k=(kh*3+kw)*64+i
        int g  = bx*256 + tid;
        int f  = g / 9216;
        int j  = g - f*9216;
        int o  = j / 144;
        int r  = j - o*144;
        int q  = r >> 4;
        int i4 = (r & 15) * 4;
        u16x4 v;
        #pragma unroll
        for (int e = 0; e < 4; ++e)
            v[e] = f2bf(ksrc[((size_t)(o*64 + i4 + e)*FF + f)*9 + q]);
        *(u16x4*)&w2[(size_t)f*36864 + j*4] = v;
        return;
    }

    int bt = bx - PW_BLOCKS;                    // 0..4095
    int b  = bt >> 9;
    int t  = bt & 511;
    const float* xb = x + (size_t)b*CIN*TFSTR + (size_t)t*FF;
    #pragma unroll
    for (int k = 0; k < 11; ++k) {
        int s = tid + k*256;
        if (s < 2624) {
            int i = s / 41;
            int u = s - i*41;
            const float* p = xb + (size_t)i*TFSTR + 4*u;
            if (u < 40) {
                f4u v = *(const f4u*)p;
                u32x2 pk = { (unsigned)f2bf(v.x) | ((unsigned)f2bf(v.y) << 16),
                             (unsigned)f2bf(v.z) | ((unsigned)f2bf(v.w) << 16) };
                *(u32x2*)&Xs[i][4*u] = pk;
            } else {
                Xs[i][160] = f2bf(*p);
            }
        }
    }
    __syncthreads();
    unsigned short* ob = x2 + (size_t)bt * FP_ * 64;
    #pragma unroll
    for (int k = 0; k < 6; ++k) {
        int s = tid + k*256;
        if (s < 1344) {
            int fp = s >> 3;
            int j  = s & 7;
            u16x8 v = {0,0,0,0,0,0,0,0};
            if (fp >= 1 && fp < 162) {
                int f = fp - 1;
                #pragma unroll
                for (int e = 0; e < 8; ++e) v[e] = Xs[j*8 + e][f];
            }
            *(u16x8*)&ob[fp*64 + j*8] = v;
        }
    }
}

// ---- ablation template of conv_mfma7 (V0 = real kernel) ----
// V0: full   V1: no stage/barriers   V2: no weight loads
// V3: no stores (asm keep-alive)     V5: improved LDS XOR key
template<int V>
__global__ __launch_bounds__(256, 3) void conv_abl(
    const unsigned short* __restrict__ x2, const unsigned short* __restrict__ w2,
    const float* __restrict__ bias, unsigned short* __restrict__ tmp)
{
    int bx  = blockIdx.x;           // 2624 = 8 * 328
    int xcd = bx & 7;
    int s   = bx >> 3;
    int fblk, g;
    if (s < 320) {
        int qd = s >> 5, w = s & 31;
        fblk = qd*4 + (w & 3);
        g    = (w >> 2)*8 + xcd;
    } else {
        fblk = 40;
        g    = (s - 320)*8 + xcd;
    }
    int b  = g >> 3;
    int t0 = (g & 7) * 64;
    int f0 = fblk * 4;

    __shared__ alignas(16) unsigned short As[2][12800];  // 51,200 B

    int tid = threadIdx.x;
    int wv  = tid >> 6;
    int l   = tid & 63;
    int l15 = l & 15;
    int lq  = l >> 4;
    int o   = wv*16 + l15;

    const unsigned short* zrow = x2 + 167*64;

    auto key4 = [](int tl, int fl) -> int {
        if constexpr (V == 5) return (tl + (tl >> 1) + fl) & 3;
        else                  return (tl + fl) & 3;
    };

    auto stage = [&](int ih) {
        #pragma unroll
        for (int it = 0; it < 7; ++it) {
            int idx = tid + it*256;
            if (idx < 1600) {
                int row = idx >> 2;
                int j   = idx & 3;
                int fl  = row / 66;
                int tl  = row - fl*66;
                int gt  = t0 - 1 + tl;
                int fp  = f0 + fl;
                bool ok = (fl < 6) && (gt >= 0) && (gt < TT);
                int key = key4(tl, fl);
                const unsigned short* src = ok
                    ? x2 + ((((size_t)b*TT + gt)*FP_ + fp)*64 + ih*32 + ((j ^ key) * 8))
                    : zrow + j*8;
                __builtin_amdgcn_global_load_lds(
                    (const __attribute__((address_space(1))) void*)src,
                    (__attribute__((address_space(3))) void*)(&As[ih][(size_t)(wv*64 + it*256)*8]),
                    16, 0, 0);
            }
        }
    };

    f32x4 acc[4][4] = {};
    const unsigned short* wb = w2 + ((size_t)f0*COUT + o)*KTOT;

    if constexpr (V != 1) {
        stage(0);
        __syncthreads();
        stage(1);
    }

    bf16x8 cst;
    #pragma unroll
    for (int e = 0; e < 8; ++e) cst[e] = (__bf16)1.0f;

    #pragma unroll
    for (int is = 0; is < 2; ++is) {
        if constexpr (V != 1) { if (is) __syncthreads(); }
        const unsigned short* bp = As[is];
        int kb = is*32 + lq*8;
        #pragma unroll
        for (int dm = 0; dm < 3; ++dm) {
            bf16x8 bw[3][4];
            #pragma unroll
            for (int dn = 0; dn < 3; ++dn)
                #pragma unroll
                for (int u = 0; u < 4; ++u) {
                    if constexpr (V == 2) bw[dn][u] = cst;
                    else bw[dn][u] = *(const bf16x8*)&wb[(size_t)u*COUT*KTOT + (dm*3+dn)*64 + kb];
                }
            #pragma unroll
            for (int mf = 0; mf < 4; ++mf) {
                int tl = mf*16 + l15 + dm;
                bf16x8 a6[6];
                #pragma unroll
                for (int v = 0; v < 6; ++v) {
                    int slot = lq ^ key4(tl, v);
                    a6[v] = *(const bf16x8*)&bp[(size_t)(v*66 + tl)*32 + slot*8];
                }
                #pragma unroll
                for (int dn = 0; dn < 3; ++dn)
                    #pragma unroll
                    for (int u = 0; u < 4; ++u)
                        acc[u][mf] = __builtin_amdgcn_mfma_f32_16x16x32_bf16(
                            a6[u + dn], bw[dn][u], acc[u][mf], 0, 0, 0);
            }
        }
    }

    if constexpr (V == 3) {
        #pragma unroll
        for (int u = 0; u < 4; ++u)
            #pragma unroll
            for (int mf = 0; mf < 4; ++mf)
                asm volatile("" :: "v"(acc[u][mf][0]), "v"(acc[u][mf][1]),
                                   "v"(acc[u][mf][2]), "v"(acc[u][mf][3]));
        return;
    }

    #pragma unroll
    for (int u = 0; u < 4; ++u) {
        int fe = f0 + u;
        if (fe < FF) {
            float bv = bias[o*FF + fe];
            size_t tb = ((size_t)b*FF + fe)*TT + t0;
            #pragma unroll
            for (int mf = 0; mf < 4; ++mf)
                #pragma unroll
                for (int rr = 0; rr < 4; ++rr) {
                    int t = mf*16 + lq*4 + rr;
                    tmp[(tb + t)*COUT + o] = f2bf(acc[u][mf][rr] + bv);
                }
        }
    }
}

// ---- finalize: tmp[b][f][t][o] bf16 -> out[b][o][t][f] f32 (bias already in) ----
__global__ __launch_bounds__(256) void finalize2(
    const unsigned short* __restrict__ tmp, float* __restrict__ out)
{
    int bx = blockIdx.x;            // 2048
    int b  = bx & 7;
    int s  = bx >> 3;
    int tb = s >> 1;
    int oh = s & 1;
    int t0 = tb * 4;
    int o0 = oh * 32;

    __shared__ unsigned short Ld[644*40];       // 51,520 B

    int tid = threadIdx.x;

    #pragma unroll
    for (int k = 0; k < 11; ++k) {
        int sl = tid + k*256;
        if (sl < 2576) {
            int f = sl >> 4;
            int r = sl & 15;
            int t = r >> 2;
            int j = r & 3;
            const unsigned short* src =
                tmp + (((size_t)b*FF + f)*TT + t0 + t)*COUT + o0 + j*8;
            int row = t*FF + f;
            *(u16x8*)&Ld[row*40 + ((j ^ (f & 3)) << 3)] = *(const u16x8*)src;
        }
    }
    __syncthreads();

    for (int ol = 0; ol < 32; ++ol) {
        int o = o0 + ol;
        float* op = out + (((size_t)b*COUT + o)*TT + t0)*FF;
        int jo = ol >> 3, o7 = ol & 7;
        #pragma unroll
        for (int k = 0; k < 3; ++k) {
            int r = tid + k*256;
            if (r < 4*FF) {
                int f = r % FF;
                op[r] = bf2f(Ld[r*40 + ((jo ^ (f & 3)) << 3) + o7]);
            }
        }
    }
}

// ---- small fallback: stages directly from f32 x; needs only w2 (12 MB ws) ----
__global__ __launch_bounds__(256) void conv_mfma(
    const float* __restrict__ x, const unsigned short* __restrict__ w2,
    const float* __restrict__ bias, float* __restrict__ out)
{
    int bx = blockIdx.x;
    int r  = bx & 7;
    int q  = bx >> 3;
    int fblk = q % 41;
    int g  = (q / 41) * 8 + r;
    int b  = g >> 3;
    int t0 = (g & 7) * 64;
    int f0 = fblk * 4;

    __shared__ unsigned short Bs[6][66][64];
    int tid = threadIdx.x;

    for (int i = 0; i < 64; i += 4) {
        #pragma unroll
        for (int pp = 0; pp < 2; ++pp) {
            int p = tid + pp*256;
            if (p < 396) {
                int tl = p / 6, fl = p % 6;
                int gt = t0 - 1 + tl;
                int gf = f0 - 1 + fl;
                bool ok = (gt >= 0) && (gt < TT) && (gf >= 0) && (gf < FF);
                const float* xp = x + (((size_t)(b*CIN + i)*TT + gt)*FF + gf);
                float v0 = ok ? xp[0]       : 0.f;
                float v1 = ok ? xp[TFSTR]   : 0.f;
                float v2 = ok ? xp[2*TFSTR] : 0.f;
                float v3 = ok ? xp[3*TFSTR] : 0.f;
                int isw = i ^ (((tl + fl) & 7) << 3);
                ushort4 pk;
                pk.x = f2bf(v0); pk.y = f2bf(v1); pk.z = f2bf(v2); pk.w = f2bf(v3);
                *reinterpret_cast<ushort4*>(&Bs[fl][tl][isw]) = pk;
            }
        }
    }
    __syncthreads();

    int wv = tid >> 6;
    int l  = tid & 63;
    int f  = f0 + wv;
    if (f >= FF) return;

    int l15 = l & 15;
    int lq  = l >> 4;
    f32x4 acc[4][4] = {};
    const unsigned short* wb = w2 + (size_t)f * (COUT * KTOT);

    #pragma unroll
    for (int dm = 0; dm < 3; ++dm)
    #pragma unroll
    for (int dn = 0; dn < 3; ++dn) {
        int fl = wv + dn;
        int kq = (dm*3 + dn) * 64;
        #pragma unroll
        for (int is = 0; is < 2; ++is) {
            int i0 = is*32 + lq*8;
            bf16x8 a[4];
            #pragma unroll
            for (int mf = 0; mf < 4; ++mf) {
                int tl  = mf*16 + l15 + dm;
                int isw = i0 ^ (((tl + fl) & 7) << 3);
                a[mf] = *(const bf16x8*)&Bs[fl][tl][isw];
            }
            int kb = kq + i0;
            #pragma unroll
            for (int nf = 0; nf < 4; ++nf) {
                bf16x8 bfr = *(const bf16x8*)&wb[(size_t)(nf*16 + l15) * KTOT + kb];
                #pragma unroll
                for (int mf = 0; mf < 4; ++mf)
                    acc[mf][nf] = __builtin_amdgcn_mfma_f32_16x16x32_bf16(
                        a[mf], bfr, acc[mf][nf], 0, 0, 0);
            }
        }
    }

    #pragma unroll
    for (int nf = 0; nf < 4; ++nf) {
        int o = nf*16 + l15;
        float bv = bias[o*FF + f];
        size_t obase = (((size_t)b*COUT + o)*TT + t0 + lq*4)*FF + f;
        #pragma unroll
        for (int mf = 0; mf < 4; ++mf)
            #pragma unroll
            for (int rr = 0; rr < 4; ++rr)
                out[obase + (size_t)(mf*16 + rr)*FF] = acc[mf][nf][rr] + bv;
    }
}

extern "C" void kernel_launch(void* const* d_in, const int* in_sizes, int n_in,
                              void* d_out, int out_size, void* d_ws, size_t ws_size,
                              hipStream_t stream)
{
    (void)in_sizes; (void)n_in; (void)out_size;
    const float* x    = (const float*)d_in[0];
    const float* k    = (const float*)d_in[1];
    const float* bias = (const float*)d_in[2];
    float* out = (float*)d_out;
    unsigned short* w2  = (unsigned short*)d_ws;
    unsigned short* x2  = (unsigned short*)((char*)d_ws + W2_BYTES);
    unsigned short* tmp = (unsigned short*)((char*)d_ws + W2_BYTES + X2_BYTES);

    bool big2 = (ws_size >= W2_BYTES + X2_BYTES + TMP_BYTES);

    prep_fused<<<big2 ? (PW_BLOCKS + 8*TT) : PW_BLOCKS, 256, 0, stream>>>(k, w2, x, x2);

    if (big2) {
        conv_abl<0><<<8*328, 256, 0, stream>>>(x2, w2, bias, tmp);   // real
        finalize2<<<2048, 256, 0, stream>>>(tmp, out);
        // ---- ablation dispatches (tmp already consumed; output unaffected) ----
        conv_abl<1><<<8*328, 256, 0, stream>>>(x2, w2, bias, tmp);   // no stage
        conv_abl<2><<<8*328, 256, 0, stream>>>(x2, w2, bias, tmp);   // no weights
        conv_abl<3><<<8*328, 256, 0, stream>>>(x2, w2, bias, tmp);   // no stores
        conv_abl<5><<<8*328, 256, 0, stream>>>(x2, w2, bias, tmp);   // new LDS key
    } else {
        conv_mfma<<<8*41*8, 256, 0, stream>>>(x, w2, bias, out);     // fallback
    }
}

// Round 9
// 261.071 us; speedup vs baseline: 2.5528x; 2.5528x over previous
//
#include <hip/hip_runtime.h>
#include <hip/hip_bf16.h>

#define CIN   64
#define COUT  64
#define TT    512
#define FF    161
#define KTOT  576          // 9 * 64
#define WST   (COUT*KTOT)  // 36864 shorts per f
#define TFSTR (TT*FF)      // 82432
#define FP_   168          // padded f dim of X2: fp = f+1, zeros at fp=0 and fp>=162

#define W2_BYTES  ((size_t)FF*COUT*KTOT*2)           // 11,870,208
#define X2_BYTES  ((size_t)8*TT*FP_*64*2)            // 88,080,384
#define TMP_BYTES ((size_t)8*FF*TT*COUT*2)           // 84,410,368
#define PW_BLOCKS 5796                               // 161*9216/256 u16x4 quads

typedef __bf16 bf16x8 __attribute__((ext_vector_type(8)));
typedef float  f32x4  __attribute__((ext_vector_type(4)));
typedef unsigned short u16x8 __attribute__((ext_vector_type(8)));
typedef unsigned short u16x4 __attribute__((ext_vector_type(4)));
typedef unsigned int   u32x2 __attribute__((ext_vector_type(2)));
typedef float f4u __attribute__((ext_vector_type(4), aligned(4)));

__device__ __forceinline__ unsigned short f2bf(float v) {
    union { float f; unsigned int u; } c; c.f = v;
    unsigned int u = c.u + 0x7FFFu + ((c.u >> 16) & 1u);   // RNE
    return (unsigned short)(u >> 16);
}
__device__ __forceinline__ float bf2f(unsigned short h) {
    union { unsigned int u; float f; } c; c.u = (unsigned)h << 16;
    return c.f;
}

// ---- fused prep: blocks [0, PW_BLOCKS) repack weights; rest transpose x ----
__global__ __launch_bounds__(256) void prep_fused(
    const float* __restrict__ ksrc, unsigned short* __restrict__ w2,
    const float* __restrict__ x, unsigned short* __restrict__ x2)
{
    __shared__ unsigned short Xs[64][172];      // 22,016 B
    int bx = blockIdx.x;
    int tid = threadIdx.x;

    if (bx < PW_BLOCKS) {                       // W2[f][o][k], k=(kh*3+kw)*64+i
        int g  = bx*256 + tid;
        int f  = g / 9216;
        int j  = g - f*9216;
        int o  = j / 144;
        int r  = j - o*144;
        int q  = r >> 4;
        int i4 = (r & 15) * 4;
        u16x4 v;
        #pragma unroll
        for (int e = 0; e < 4; ++e)
            v[e] = f2bf(ksrc[((size_t)(o*64 + i4 + e)*FF + f)*9 + q]);
        *(u16x4*)&w2[(size_t)f*36864 + j*4] = v;
        return;
    }

    int bt = bx - PW_BLOCKS;                    // 0..4095
    int b  = bt >> 9;
    int t  = bt & 511;
    const float* xb = x + (size_t)b*CIN*TFSTR + (size_t)t*FF;
    #pragma unroll
    for (int k = 0; k < 11; ++k) {
        int s = tid + k*256;
        if (s < 2624) {
            int i = s / 41;
            int u = s - i*41;
            const float* p = xb + (size_t)i*TFSTR + 4*u;
            if (u < 40) {
                f4u v = *(const f4u*)p;
                u32x2 pk = { (unsigned)f2bf(v.x) | ((unsigned)f2bf(v.y) << 16),
                             (unsigned)f2bf(v.z) | ((unsigned)f2bf(v.w) << 16) };
                *(u32x2*)&Xs[i][4*u] = pk;
            } else {
                Xs[i][160] = f2bf(*p);
            }
        }
    }
    __syncthreads();
    unsigned short* ob = x2 + (size_t)bt * FP_ * 64;
    #pragma unroll
    for (int k = 0; k < 6; ++k) {
        int s = tid + k*256;
        if (s < 1344) {
            int fp = s >> 3;
            int j  = s & 7;
            u16x8 v = {0,0,0,0,0,0,0,0};
            if (fp >= 1 && fp < 162) {
                int f = fp - 1;
                #pragma unroll
                for (int e = 0; e < 8; ++e) v[e] = Xs[j*8 + e][f];
            }
            *(u16x8*)&ob[fp*64 + j*8] = v;
        }
    }
}

// ---- conv: 2f x 64o x 64t per block, 4 waves = o-quarters ----
// 33.8 KB LDS -> 4 blocks/CU = 16 waves/CU. Whole tile staged once, ONE
// barrier, then 6 uninterrupted (is,dm) phases with a 2-deep explicit
// weight double-buffer (dep-chain halved vs round 7).
__global__ __launch_bounds__(256, 4) void conv_mfma8(
    const unsigned short* __restrict__ x2, const unsigned short* __restrict__ w2,
    const float* __restrict__ bias, unsigned short* __restrict__ tmp)
{
    int bx   = blockIdx.x;          // 5184 = 8 xcd * 81 fblk * 8 tq
    int b    = bx & 7;              // XCD = batch
    int r    = bx >> 3;             // fblk-outer, tq-inner: weight window L2-hot
    int tq   = r & 7;
    int fblk = r >> 3;              // 0..80
    int t0   = tq * 64;
    int f0   = fblk * 2;

    // LDS rows = fl*66 + tl (fl 0..3, tl 0..65), 64 bf16 (128B) per row
    __shared__ alignas(16) unsigned short As[264*64];   // 33,792 B

    int tid = threadIdx.x;
    int wq  = tid >> 6;             // o-quarter
    int l   = tid & 63;
    int l15 = l & 15;
    int lq  = l >> 4;
    int o   = wq*16 + l15;

    const unsigned short* zrow = x2 + 167*64;   // guaranteed-zero row

    // ---- stage whole tile: 264 rows x 8 slots of 16B = 2112 ----
    #pragma unroll
    for (int it = 0; it < 9; ++it) {
        int idx = tid + it*256;
        if (idx < 2112) {
            int row = idx >> 3;
            int j   = idx & 7;
            int fl  = row / 66;
            int tl  = row - fl*66;
            int gt  = t0 - 1 + tl;
            int fp  = f0 + fl;                  // <= 163 < FP_
            bool ok = (gt >= 0) && (gt < TT);
            int key = (tl + fl) & 7;
            const unsigned short* src = ok
                ? x2 + ((((size_t)b*TT + gt)*FP_ + fp)*64 + ((j ^ key) * 8))
                : zrow + j*8;
            __builtin_amdgcn_global_load_lds(
                (const __attribute__((address_space(1))) void*)src,
                (__attribute__((address_space(3))) void*)(As + (size_t)idx*8),
                16, 0, 0);
        }
    }
    __syncthreads();

    f32x4 acc[2][4] = {};           // [u=f][mf]
    const unsigned short* wb = w2 + ((size_t)f0*COUT + o)*KTOT;
    // (fblk==80: u=1 weight reads run past w2 into x2 region of d_ws: safe, discarded)

    bf16x8 bw0[6], bw1[6];
    auto ldw = [&](bf16x8 (&dst)[6], int p) {   // p constant under full unroll
        int is = p / 3, dm = p - (p/3)*3;
        int kb = is*32 + lq*8;
        #pragma unroll
        for (int dn = 0; dn < 3; ++dn)
            #pragma unroll
            for (int u = 0; u < 2; ++u)
                dst[dn*2 + u] = *(const bf16x8*)&wb[(size_t)u*WST + (dm*3 + dn)*64 + kb];
    };

    ldw(bw0, 0);
    #pragma unroll
    for (int p = 0; p < 6; ++p) {
        if (p < 5) {
            if (p & 1) ldw(bw0, p + 1); else ldw(bw1, p + 1);
        }
        int is = p / 3, dm = p - (p/3)*3;
        int sbase = is*4 + lq;
        #pragma unroll
        for (int mf = 0; mf < 4; ++mf) {
            int tl = mf*16 + l15 + dm;
            bf16x8 a4[4];
            #pragma unroll
            for (int fl = 0; fl < 4; ++fl) {
                int slot = sbase ^ ((tl + fl) & 7);
                a4[fl] = *(const bf16x8*)&As[(size_t)(fl*66 + tl)*64 + slot*8];
            }
            #pragma unroll
            for (int dn = 0; dn < 3; ++dn)
                #pragma unroll
                for (int u = 0; u < 2; ++u)
                    acc[u][mf] = __builtin_amdgcn_mfma_f32_16x16x32_bf16(
                        a4[u + dn], (p & 1) ? bw1[dn*2 + u] : bw0[dn*2 + u],
                        acc[u][mf], 0, 0, 0);
        }
    }

    // ---- epilogue: bias + bf16 -> tmp[b][f][t][o] ----
    #pragma unroll
    for (int u = 0; u < 2; ++u) {
        int fe = f0 + u;
        if (fe < FF) {                          // block-uniform guard (fblk 80)
            float bv = bias[o*FF + fe];
            size_t tb = ((size_t)b*FF + fe)*TT + t0;
            #pragma unroll
            for (int mf = 0; mf < 4; ++mf)
                #pragma unroll
                for (int rr = 0; rr < 4; ++rr) {
                    int t = mf*16 + lq*4 + rr;
                    tmp[(tb + t)*COUT + o] = f2bf(acc[u][mf][rr] + bv);
                }
        }
    }
}

// ---- finalize: tmp[b][f][t][o] bf16 -> out[b][o][t][f] f32 (bias already in) ----
__global__ __launch_bounds__(256) void finalize2(
    const unsigned short* __restrict__ tmp, float* __restrict__ out)
{
    int bx = blockIdx.x;            // 2048
    int b  = bx & 7;
    int s  = bx >> 3;
    int tb = s >> 1;
    int oh = s & 1;
    int t0 = tb * 4;
    int o0 = oh * 32;

    __shared__ unsigned short Ld[644*40];       // 51,520 B

    int tid = threadIdx.x;

    #pragma unroll
    for (int k = 0; k < 11; ++k) {
        int sl = tid + k*256;
        if (sl < 2576) {
            int f = sl >> 4;
            int r = sl & 15;
            int t = r >> 2;
            int j = r & 3;
            const unsigned short* src =
                tmp + (((size_t)b*FF + f)*TT + t0 + t)*COUT + o0 + j*8;
            int row = t*FF + f;
            *(u16x8*)&Ld[row*40 + ((j ^ (f & 3)) << 3)] = *(const u16x8*)src;
        }
    }
    __syncthreads();

    for (int ol = 0; ol < 32; ++ol) {
        int o = o0 + ol;
        float* op = out + (((size_t)b*COUT + o)*TT + t0)*FF;
        int jo = ol >> 3, o7 = ol & 7;
        #pragma unroll
        for (int k = 0; k < 3; ++k) {
            int r = tid + k*256;
            if (r < 4*FF) {
                int f = r % FF;
                op[r] = bf2f(Ld[r*40 + ((jo ^ (f & 3)) << 3) + o7]);
            }
        }
    }
}

// ---- small fallback: stages directly from f32 x; needs only w2 (12 MB ws) ----
__global__ __launch_bounds__(256) void conv_mfma(
    const float* __restrict__ x, const unsigned short* __restrict__ w2,
    const float* __restrict__ bias, float* __restrict__ out)
{
    int bx = blockIdx.x;
    int r  = bx & 7;
    int q  = bx >> 3;
    int fblk = q % 41;
    int g  = (q / 41) * 8 + r;
    int b  = g >> 3;
    int t0 = (g & 7) * 64;
    int f0 = fblk * 4;

    __shared__ unsigned short Bs[6][66][64];
    int tid = threadIdx.x;

    for (int i = 0; i < 64; i += 4) {
        #pragma unroll
        for (int pp = 0; pp < 2; ++pp) {
            int p = tid + pp*256;
            if (p < 396) {
                int tl = p / 6, fl = p % 6;
                int gt = t0 - 1 + tl;
                int gf = f0 - 1 + fl;
                bool ok = (gt >= 0) && (gt < TT) && (gf >= 0) && (gf < FF);
                const float* xp = x + (((size_t)(b*CIN + i)*TT + gt)*FF + gf);
                float v0 = ok ? xp[0]       : 0.f;
                float v1 = ok ? xp[TFSTR]   : 0.f;
                float v2 = ok ? xp[2*TFSTR] : 0.f;
                float v3 = ok ? xp[3*TFSTR] : 0.f;
                int isw = i ^ (((tl + fl) & 7) << 3);
                ushort4 pk;
                pk.x = f2bf(v0); pk.y = f2bf(v1); pk.z = f2bf(v2); pk.w = f2bf(v3);
                *reinterpret_cast<ushort4*>(&Bs[fl][tl][isw]) = pk;
            }
        }
    }
    __syncthreads();

    int wv = tid >> 6;
    int l  = tid & 63;
    int f  = f0 + wv;
    if (f >= FF) return;

    int l15 = l & 15;
    int lq  = l >> 4;
    f32x4 acc[4][4] = {};
    const unsigned short* wb = w2 + (size_t)f * (COUT * KTOT);

    #pragma unroll
    for (int dm = 0; dm < 3; ++dm)
    #pragma unroll
    for (int dn = 0; dn < 3; ++dn) {
        int fl = wv + dn;
        int kq = (dm*3 + dn) * 64;
        #pragma unroll
        for (int is = 0; is < 2; ++is) {
            int i0 = is*32 + lq*8;
            bf16x8 a[4];
            #pragma unroll
            for (int mf = 0; mf < 4; ++mf) {
                int tl  = mf*16 + l15 + dm;
                int isw = i0 ^ (((tl + fl) & 7) << 3);
                a[mf] = *(const bf16x8*)&Bs[fl][tl][isw];
            }
            int kb = kq + i0;
            #pragma unroll
            for (int nf = 0; nf < 4; ++nf) {
                bf16x8 bfr = *(const bf16x8*)&wb[(size_t)(nf*16 + l15) * KTOT + kb];
                #pragma unroll
                for (int mf = 0; mf < 4; ++mf)
                    acc[mf][nf] = __builtin_amdgcn_mfma_f32_16x16x32_bf16(
                        a[mf], bfr, acc[mf][nf], 0, 0, 0);
            }
        }
    }

    #pragma unroll
    for (int nf = 0; nf < 4; ++nf) {
        int o = nf*16 + l15;
        float bv = bias[o*FF + f];
        size_t obase = (((size_t)b*COUT + o)*TT + t0 + lq*4)*FF + f;
        #pragma unroll
        for (int mf = 0; mf < 4; ++mf)
            #pragma unroll
            for (int rr = 0; rr < 4; ++rr)
                out[obase + (size_t)(mf*16 + rr)*FF] = acc[mf][nf][rr] + bv;
    }
}

extern "C" void kernel_launch(void* const* d_in, const int* in_sizes, int n_in,
                              void* d_out, int out_size, void* d_ws, size_t ws_size,
                              hipStream_t stream)
{
    (void)in_sizes; (void)n_in; (void)out_size;
    const float* x    = (const float*)d_in[0];
    const float* k    = (const float*)d_in[1];
    const float* bias = (const float*)d_in[2];
    float* out = (float*)d_out;
    unsigned short* w2  = (unsigned short*)d_ws;
    unsigned short* x2  = (unsigned short*)((char*)d_ws + W2_BYTES);
    unsigned short* tmp = (unsigned short*)((char*)d_ws + W2_BYTES + X2_BYTES);

    bool big2 = (ws_size >= W2_BYTES + X2_BYTES + TMP_BYTES);

    prep_fused<<<big2 ? (PW_BLOCKS + 8*TT) : PW_BLOCKS, 256, 0, stream>>>(k, w2, x, x2);

    if (big2) {
        conv_mfma8<<<5184, 256, 0, stream>>>(x2, w2, bias, tmp);   // 4 blocks/CU
        finalize2<<<2048, 256, 0, stream>>>(tmp, out);
    } else {
        conv_mfma<<<8*41*8, 256, 0, stream>>>(x, w2, bias, out);   // fallback
    }
}